// Round 19
// baseline (136.191 us; speedup 1.0000x reference)
//
#include <hip/hip_runtime.h>
#include <math.h>

#define D_MODEL 1024
#define N_HEADS 16
#define DKH     64
#define BATCH   2
#define SEQ     2048
#define NT128   (SEQ/128)         // 16 q-tiles of 128
#define PARTS_PER_BH 40           // sum over t of ceil(2(t+1)/8)

typedef unsigned short u16;
typedef unsigned long long u64;
typedef __attribute__((ext_vector_type(8))) short short8;
typedef __attribute__((ext_vector_type(4))) short s4v;
typedef __attribute__((ext_vector_type(4))) float f32x4;

__device__ __forceinline__ u16 f2bf(float f) {
    unsigned u = __float_as_uint(f);
    u += 0x7fffu + ((u >> 16) & 1u);
    return (u16)(u >> 16);
}
__device__ __forceinline__ float bf2f(u16 x) {
    return __int_as_float(((int)x) << 16);
}

// raw v_exp_f32 (2^x). args bounded; denorm-range flush is harmless here.
__device__ __forceinline__ float fexp2(float x) {
#if __has_builtin(__builtin_amdgcn_exp2f)
    return __builtin_amdgcn_exp2f(x);
#else
    return exp2f(x);
#endif
}

__device__ __forceinline__ void gll16(const void* g, void* l) {
    __builtin_amdgcn_global_load_lds((const __attribute__((address_space(1))) void*)g,
                                     (__attribute__((address_space(3))) void*)l, 16, 0, 0);
}

// 16x16x16 bf16 MFMA (K=16): builtin if present, else raw asm.
__device__ __forceinline__ f32x4 mfma16(s4v a, s4v b, f32x4 c) {
#if __has_builtin(__builtin_amdgcn_mfma_f32_16x16x16bf16_1k)
    return __builtin_amdgcn_mfma_f32_16x16x16bf16_1k(a, b, c, 0, 0, 0);
#elif __has_builtin(__builtin_amdgcn_mfma_f32_16x16x16_bf16)
    return __builtin_amdgcn_mfma_f32_16x16x16_bf16(a, b, c, 0, 0, 0);
#else
    f32x4 d;
    asm("v_mfma_f32_16x16x16_bf16 %0, %1, %2, %3" : "=v"(d) : "v"(a), "v"(b), "v"(c));
    return d;
#endif
}

// V column permutation baked into Vt: 4-elem granularity so PV ds_read_b64
// gets 4 bits of lane->bank variation (conflict-free; verified: 4.3M -> 0).
__device__ __forceinline__ int vperm(int d) {
    return ((d & 7) << 3) | (((d >> 3) & 1) << 2);
}

// ---------------------------------------------------------------------------
// fp32 -> bf16 convert: q,k,v (4M elems each) + w_q,w_k,w_v,w_o (1M each)
// ---------------------------------------------------------------------------
__global__ __launch_bounds__(256)
void convert_kernel(const float* __restrict__ q, const float* __restrict__ k,
                    const float* __restrict__ v, const float* __restrict__ wq,
                    const float* __restrict__ wk, const float* __restrict__ wv,
                    const float* __restrict__ wo,
                    u16* __restrict__ qb, u16* __restrict__ kb, u16* __restrict__ vb,
                    u16* __restrict__ wqb, u16* __restrict__ wkb,
                    u16* __restrict__ wvb, u16* __restrict__ wob)
{
    const size_t NV = ((size_t)16 << 20) >> 3;   // total 16M elems in vec8 units
    for (size_t i = (size_t)blockIdx.x * blockDim.x + threadIdx.x; i < NV;
         i += (size_t)gridDim.x * blockDim.x) {
        const size_t e = i << 3;
        const float* s; u16* d; size_t off;
        if (e < ((size_t)12 << 20)) {
            const int seg = (int)(e >> 22);
            off = e & (((size_t)1 << 22) - 1);
            s = seg == 0 ? q : seg == 1 ? k : v;
            d = seg == 0 ? qb : seg == 1 ? kb : vb;
        } else {
            const size_t r = e - ((size_t)12 << 20);
            const int seg = (int)(r >> 20);
            off = r & (((size_t)1 << 20) - 1);
            s = seg == 0 ? wq : seg == 1 ? wk : seg == 2 ? wv : wo;
            d = seg == 0 ? wqb : seg == 1 ? wkb : seg == 2 ? wvb : wob;
        }
        const float4 f0 = *(const float4*)(s + off);
        const float4 f1 = *(const float4*)(s + off + 4);
        short8 o;
        o[0]=(short)f2bf(f0.x); o[1]=(short)f2bf(f0.y); o[2]=(short)f2bf(f0.z); o[3]=(short)f2bf(f0.w);
        o[4]=(short)f2bf(f1.x); o[5]=(short)f2bf(f1.y); o[6]=(short)f2bf(f1.z); o[7]=(short)f2bf(f1.w);
        *(short8*)(d + off) = o;
    }
}

// ---------------------------------------------------------------------------
// GEMM core: 128x128 tile, BK=32, 4 waves, global_load_lds staging.
// ---------------------------------------------------------------------------
#define GEMM_PREAMBLE                                                            \
    __shared__ __align__(16) u16 As[2][128][32];                                 \
    __shared__ __align__(16) u16 Bs[2][128][32];                                 \
    const int tid  = threadIdx.x;                                                \
    const int lane = tid & 63;                                                   \
    const int wid  = tid >> 6;                                                   \
    const int wm   = wid >> 1, wn = wid & 1;                                     \
    const int lr   = lane & 15, lg = lane >> 4;                                  \
    const int mb   = blockIdx.x * 128, nb = blockIdx.y * 128;                    \
    const int g_row = lane >> 2;                                                 \
    const int g_col = (lane & 3) << 3;                                           \
    const u16* Ab = A  + (size_t)mb * K;                                         \
    const u16* Bb = Bw + (size_t)nb * K;                                         \
    f32x4 acc[4][4];                                                             \
    _Pragma("unroll")                                                            \
    for (int i = 0; i < 4; ++i)                                                  \
        _Pragma("unroll")                                                        \
        for (int j = 0; j < 4; ++j) { f32x4 z = {0.f,0.f,0.f,0.f}; acc[i][j] = z; }

#define STAGE(buf, kt)                                                           \
    {                                                                            \
        _Pragma("unroll")                                                        \
        for (int t = 0; t < 2; ++t) {                                            \
            const int r0 = t*64 + wid*16;                                        \
            gll16(&Ab[(size_t)(r0 + g_row)*K + (kt) + g_col], &As[buf][r0][0]);  \
            gll16(&Bb[(size_t)(r0 + g_row)*K + (kt) + g_col], &Bs[buf][r0][0]);  \
        }                                                                        \
    }

#define GEMM_MAINLOOP                                                            \
    STAGE(0, 0)                                                                  \
    __syncthreads();                                                             \
    const int NK = K >> 5;                                                       \
    for (int it = 0; it < NK; ++it) {                                            \
        const int c = it & 1;                                                    \
        if (it + 1 < NK) STAGE(c ^ 1, (it + 1) << 5)                             \
        short8 a[4], b[4];                                                       \
        _Pragma("unroll")                                                        \
        for (int i = 0; i < 4; ++i) a[i] = *(const short8*)&As[c][wm*64 + i*16 + lr][lg*8]; \
        _Pragma("unroll")                                                        \
        for (int j = 0; j < 4; ++j) b[j] = *(const short8*)&Bs[c][wn*64 + j*16 + lr][lg*8]; \
        _Pragma("unroll")                                                        \
        for (int i = 0; i < 4; ++i)                                              \
            _Pragma("unroll")                                                    \
            for (int j = 0; j < 4; ++j)                                          \
                acc[i][j] = __builtin_amdgcn_mfma_f32_16x16x32_bf16(a[i], b[j], acc[i][j], 0, 0, 0); \
        __syncthreads();                                                         \
    }

// Batched Q/K/V projection: blockIdx.z selects {q,k,v}.  3 blocks/CU.
// Q carries 0.125 * log2(e) so flash softmax runs in exp2 domain.
// V (z==2) is stored transposed (B,H,dk,S) with the vperm column shuffle
// baked in (bank-conflict-free PV b64 reads in flash).
__global__ __launch_bounds__(256, 3)
void gemm_qkv_kernel(const u16* __restrict__ qb, const u16* __restrict__ kb,
                     const u16* __restrict__ vb, const u16* __restrict__ wqb,
                     const u16* __restrict__ wkb, const u16* __restrict__ wvb,
                     const float* __restrict__ b_q, const float* __restrict__ b_k,
                     const float* __restrict__ b_v,
                     u16* __restrict__ Qh, u16* __restrict__ Kh, u16* __restrict__ Vt,
                     int M, int N, int K)
{
    const int z = blockIdx.z;
    const u16* A    = z == 0 ? qb  : z == 1 ? kb  : vb;
    const u16* Bw   = z == 0 ? wqb : z == 1 ? wkb : wvb;
    const float* bias = z == 0 ? b_q : z == 1 ? b_k : b_v;
    u16* dst        = z == 0 ? Qh  : z == 1 ? Kh  : Vt;
    const float scale = z == 0 ? 0.18033688f : 1.0f;  // 0.125 * log2(e)

    GEMM_PREAMBLE
    GEMM_MAINLOOP

    #pragma unroll
    for (int i = 0; i < 4; ++i) {
        #pragma unroll
        for (int j = 0; j < 4; ++j) {
            const int mbase = mb + wm*64 + i*16 + lg*4;
            const int n     = nb + wn*64 + j*16 + lr;
            const float bn  = bias[n];
            const int h = n >> 6, d = n & 63;
            #pragma unroll
            for (int r = 0; r < 4; ++r) {
                const int m = mbase + r;
                const int b = m >> 11, s = m & (SEQ - 1);
                const float val = (acc[i][j][r] + bn) * scale;
                if (z == 2) {   // V transposed (B,H,dk,S), vperm'd columns
                    const int sp = (s & ~63) | ((s & 63) ^ vperm(d));
                    dst[(((size_t)(b*N_HEADS + h))*DKH + d)*SEQ + sp] = f2bf(val);
                } else {        // Q,K (B,H,S,dk)
                    dst[(((size_t)(b*N_HEADS + h))*SEQ + s)*DKH + d] = f2bf(val);
                }
            }
        }
    }
}

// Output projection: 64x64 tile -> 1024 blocks (4/CU co-residency; was 2/CU
// at 128x64 -- this kernel is latency-limited, wave count wins).
__global__ __launch_bounds__(256)
void gemm_out_kernel(const u16* __restrict__ A, const u16* __restrict__ Bw,
                     const float* __restrict__ bias, float* __restrict__ dst,
                     int M, int N, int K)
{
    __shared__ __align__(16) u16 As[2][64][32];
    __shared__ __align__(16) u16 Bs[2][64][32];

    const int tid  = threadIdx.x;
    const int lane = tid & 63;
    const int wid  = tid >> 6;                   // 0..3
    const int wm   = wid >> 1, wn = wid & 1;     // 2x2 waves over 64x64
    const int lr   = lane & 15, lg = lane >> 4;
    const int mb   = blockIdx.x * 64, nb = blockIdx.y * 64;
    const int g_row = lane >> 2;                 // 0..15
    const int g_col = (lane & 3) << 3;

    const u16* Ab = A  + (size_t)mb * K;
    const u16* Bb = Bw + (size_t)nb * K;

    f32x4 acc[2][2];
    #pragma unroll
    for (int i = 0; i < 2; ++i)
        #pragma unroll
        for (int j = 0; j < 2; ++j) { f32x4 z = {0.f,0.f,0.f,0.f}; acc[i][j] = z; }

#define OSTAGE(buf, kt)                                                          \
    {                                                                            \
        gll16(&Ab[(size_t)(wid*16 + g_row)*K + (kt) + g_col], &As[buf][wid*16][0]); \
        gll16(&Bb[(size_t)(wid*16 + g_row)*K + (kt) + g_col], &Bs[buf][wid*16][0]); \
    }

    OSTAGE(0, 0)
    __syncthreads();

    const int NK = K >> 5;
    for (int it = 0; it < NK; ++it) {
        const int c = it & 1;
        if (it + 1 < NK) OSTAGE(c ^ 1, (it + 1) << 5)

        short8 a[2], b[2];
        #pragma unroll
        for (int i = 0; i < 2; ++i) a[i] = *(const short8*)&As[c][wm*32 + i*16 + lr][lg*8];
        #pragma unroll
        for (int j = 0; j < 2; ++j) b[j] = *(const short8*)&Bs[c][wn*32 + j*16 + lr][lg*8];
        #pragma unroll
        for (int i = 0; i < 2; ++i)
            #pragma unroll
            for (int j = 0; j < 2; ++j)
                acc[i][j] = __builtin_amdgcn_mfma_f32_16x16x32_bf16(a[i], b[j], acc[i][j], 0, 0, 0);

        __syncthreads();
    }
#undef OSTAGE

    #pragma unroll
    for (int i = 0; i < 2; ++i) {
        #pragma unroll
        for (int j = 0; j < 2; ++j) {
            const int mbase = mb + wm*32 + i*16 + lg*4;
            const int n     = nb + wn*32 + j*16 + lr;
            const float bn  = bias[n];
            #pragma unroll
            for (int r = 0; r < 4; ++r)
                dst[(size_t)(mbase + r) * N + n] = acc[i][j][r] + bn;
        }
    }
}

// ---------------------------------------------------------------------------
// one attention step for TWO 16-row q-groups sharing K/V fragments,
// SPECULATIVE-EXP form (exp2 domain, raw v_exp_f32):
//  - each K frag read feeds 4 QK MFMAs (2 per group)
//  - each V b64 read feeds 2 PV MFMAs (one per group)
//  - -m folded into QK C-init; P computed immediately; post-hoc ballot/rescale
// This halves the per-q-row LDS read cost (the kernel's throughput floor).
// ---------------------------------------------------------------------------
__device__ __forceinline__ void attn_step2(
    const short8& aq00, const short8& aq01,
    const short8& aq10, const short8& aq11,
    f32x4 (&o0)[4], f32x4 (&o1)[4],
    float& osum0, float& osum1, float& m0, float& m1,
    const u16 (*__restrict__ Kl)[64], const u16 (*__restrict__ Vl)[64],
    int kvb, int qbw0, int qbw1, int lr, int lg)
{
    const int ksw  = (lr & 7) << 3;
    const int pvsw = vperm(lr);
    const float nm0 = -m0, nm1 = -m1;
    f32x4 st0[4], st1[4];
    __builtin_amdgcn_s_setprio(1);
    #pragma unroll
    for (int c = 0; c < 4; ++c) {
        const int kr = c*16 + lr;
        short8 k0 = *(const short8*)&Kl[kr][( 0 + lg*8) ^ ksw];
        short8 k1 = *(const short8*)&Kl[kr][(32 + lg*8) ^ ksw];
        f32x4 z0 = {nm0, nm0, nm0, nm0};
        f32x4 z1 = {nm1, nm1, nm1, nm1};
        z0 = __builtin_amdgcn_mfma_f32_16x16x32_bf16(k0, aq00, z0, 0, 0, 0);
        z1 = __builtin_amdgcn_mfma_f32_16x16x32_bf16(k0, aq10, z1, 0, 0, 0);
        z0 = __builtin_amdgcn_mfma_f32_16x16x32_bf16(k1, aq01, z0, 0, 0, 0);
        z1 = __builtin_amdgcn_mfma_f32_16x16x32_bf16(k1, aq11, z1, 0, 0, 0);
        st0[c] = z0; st1[c] = z1;
    }
    __builtin_amdgcn_s_setprio(0);

    // causal mask per group: kv = kvb + c*16 + lg*4 + r, q = qbw_g + lr
    if (kvb + 63 > qbw0) {
        #pragma unroll
        for (int c = 0; c < 4; ++c)
            #pragma unroll
            for (int r = 0; r < 4; ++r)
                if (kvb + c*16 + lg*4 + r > qbw0 + lr) st0[c][r] = -INFINITY;
    }
    if (kvb + 63 > qbw1) {
        #pragma unroll
        for (int c = 0; c < 4; ++c)
            #pragma unroll
            for (int r = 0; r < 4; ++r)
                if (kvb + c*16 + lg*4 + r > qbw1 + lr) st1[c][r] = -INFINITY;
    }

    // speculative P with OLD m, per c-block (independent chains)
    s4v av0[4], av1[4];
    float sum0 = 0.f, sum1 = 0.f;
    float tl0 = -INFINITY, tl1 = -INFINITY;
    #pragma unroll
    for (int c = 0; c < 4; ++c) {
        const float p0 = fexp2(st0[c][0]);
        const float p1 = fexp2(st0[c][1]);
        const float p2 = fexp2(st0[c][2]);
        const float p3 = fexp2(st0[c][3]);
        sum0 += (p0 + p1) + (p2 + p3);
        tl0 = fmaxf(tl0, fmaxf(fmaxf(st0[c][0], st0[c][1]), fmaxf(st0[c][2], st0[c][3])));
        unsigned lo, hi;
        asm("v_cvt_pk_bf16_f32 %0, %1, %2" : "=v"(lo) : "v"(p0), "v"(p1));
        asm("v_cvt_pk_bf16_f32 %0, %1, %2" : "=v"(hi) : "v"(p2), "v"(p3));
        union { unsigned u[2]; s4v s; } uu; uu.u[0] = lo; uu.u[1] = hi;
        av0[c] = uu.s;
    }
    #pragma unroll
    for (int c = 0; c < 4; ++c) {
        const float p0 = fexp2(st1[c][0]);
        const float p1 = fexp2(st1[c][1]);
        const float p2 = fexp2(st1[c][2]);
        const float p3 = fexp2(st1[c][3]);
        sum1 += (p0 + p1) + (p2 + p3);
        tl1 = fmaxf(tl1, fmaxf(fmaxf(st1[c][0], st1[c][1]), fmaxf(st1[c][2], st1[c][3])));
        unsigned lo, hi;
        asm("v_cvt_pk_bf16_f32 %0, %1, %2" : "=v"(lo) : "v"(p0), "v"(p1));
        asm("v_cvt_pk_bf16_f32 %0, %1, %2" : "=v"(hi) : "v"(p2), "v"(p3));
        union { unsigned u[2]; s4v s; } uu; uu.u[0] = lo; uu.u[1] = hi;
        av1[c] = uu.s;
    }
    osum0 += sum0; osum1 += sum1;

    // O += P @ V : each V b64 read feeds BOTH groups
    __builtin_amdgcn_s_setprio(1);
    #pragma unroll
    for (int c = 0; c < 4; ++c) {
        #pragma unroll
        for (int db = 0; db < 4; ++db) {
            union { u64 q; s4v s; } bv;
            bv.q = *(const u64*)&Vl[db*16 + lr][(c*16 + lg*4) ^ pvsw];
            o0[db] = mfma16(av0[c], bv.s, o0[db]);
            o1[db] = mfma16(av1[c], bv.s, o1[db]);
        }
    }
    __builtin_amdgcn_s_setprio(0);

    // post-hoc rescale (rare); re-bases history including this tile
    if (__any(tl0 > 11.5f)) {
        float tm = fmaxf(tl0, __shfl_xor(tl0, 16));
        tm = fmaxf(tm, __shfl_xor(tm, 32));
        tm = fmaxf(tm, 0.f);
        const float f = fexp2(-tm);
        m0 += tm; osum0 *= f;
        float af[4];
        #pragma unroll
        for (int r = 0; r < 4; ++r)
            af[r] = __shfl(f, (lg << 4) | (lg*4 + r));
        #pragma unroll
        for (int db = 0; db < 4; ++db)
            #pragma unroll
            for (int r = 0; r < 4; ++r) o0[db][r] *= af[r];
    }
    if (__any(tl1 > 11.5f)) {
        float tm = fmaxf(tl1, __shfl_xor(tl1, 16));
        tm = fmaxf(tm, __shfl_xor(tm, 32));
        tm = fmaxf(tm, 0.f);
        const float f = fexp2(-tm);
        m1 += tm; osum1 *= f;
        float af[4];
        #pragma unroll
        for (int r = 0; r < 4; ++r)
            af[r] = __shfl(f, (lg << 4) | (lg*4 + r));
        #pragma unroll
        for (int db = 0; db < 4; ++db)
            #pragma unroll
            for (int r = 0; r < 4; ++r) o1[db][r] *= af[r];
    }
}

// ---------------------------------------------------------------------------
// Split-KV flash attention: block = (bh, q-tile t of 128 rows, kv-chunk of
// up to 8 64-wide tiles).  SAME 1280-block grid / LPT / partial layout as the
// proven config, but 256 threads: 4 waves x 32 q-rows (2 groups per wave)
// sharing K/V fragments -> halves the per-q-row LDS read floor.
// K source column pre-swizzled; V layout pre-permuted.  Double-buffered,
// ONE __syncthreads per kv-tile.  ~33KB LDS.  No forced min-waves.
// ---------------------------------------------------------------------------
__global__ __launch_bounds__(256)
void flash_split_kernel(const u16* __restrict__ Qh, const u16* __restrict__ Kh,
                        const u16* __restrict__ Vt, u16* __restrict__ part_o,
                        float* __restrict__ part_ms)
{
    __shared__ __align__(16) u16 Kl[2][64][64];
    __shared__ __align__(16) u16 Vl[2][64][64];

    const int x = 39 - blockIdx.x;          // LPT: largest chunks dispatch first
    int t, ch;
    if      (x <  4) { t = x;                 ch = 0;        }
    else if (x < 12) { t = 4 + ((x-4) >> 1);  ch = (x-4)&1;  }
    else if (x < 24) { t = 8 + (x-12)/3;      ch = (x-12)%3; }
    else             { t = 12 + ((x-24) >> 2); ch = (x-24)&3; }

    const int tid  = threadIdx.x;
    const int lane = tid & 63;
    const int wid  = tid >> 6;              // 0..3
    const int lr   = lane & 15, lg = lane >> 4;
    const int bh   = blockIdx.y;            // b*H + h
    const int qbw0 = t*128 + wid*32;        // wave's group-0 first q row
    const int qbw1 = qbw0 + 16;             // group-1
    const size_t base = (size_t)bh * SEQ * DKH;

    const int c0      = ch * 8;             // first kv tile (64-wide) of chunk
    const int nc_here = min(8, 2*(t+1) - c0);

    // staging: wave wid DMAs rows wid*16..wid*16+15 of K and of V (2KB each,
    // 2 gll16 per matrix).  K: source column pre-swizzled; V: linear.
    const int srow8 = lane >> 3;                    // 0..7
    const int kcol  = ((lane & 7) << 3) ^ (srow8 << 3);   // K swizzled col
    const int vcol  = (lane & 7) << 3;                    // V linear col
    const int sr0   = wid*16 + srow8;               // rows covered: sr0, sr0+8

#define FSTAGE(buf, kb)                                                          \
    {                                                                            \
        gll16(&Kh[base + (size_t)((kb) + sr0    )*DKH + kcol], &Kl[buf][wid*16    ][0]); \
        gll16(&Kh[base + (size_t)((kb) + sr0 + 8)*DKH + kcol], &Kl[buf][wid*16 + 8][0]); \
        gll16(&Vt[base + (size_t)(sr0    )*SEQ + (kb) + vcol], &Vl[buf][wid*16    ][0]); \
        gll16(&Vt[base + (size_t)(sr0 + 8)*SEQ + (kb) + vcol], &Vl[buf][wid*16 + 8][0]); \
    }

    short8 aq00 = *(const short8*)&Qh[base + (size_t)(qbw0 + lr)*DKH +  0 + lg*8];
    short8 aq01 = *(const short8*)&Qh[base + (size_t)(qbw0 + lr)*DKH + 32 + lg*8];
    short8 aq10 = *(const short8*)&Qh[base + (size_t)(qbw1 + lr)*DKH +  0 + lg*8];
    short8 aq11 = *(const short8*)&Qh[base + (size_t)(qbw1 + lr)*DKH + 32 + lg*8];

    f32x4 o0[4], o1[4];
    float osum0 = 0.f, osum1 = 0.f, m0 = 0.f, m1 = 0.f;   // spec-exp form
    {
        f32x4 z = {0.f,0.f,0.f,0.f};
        #pragma unroll
        for (int db = 0; db < 4; ++db) { o0[db] = z; o1[db] = z; }
    }

    FSTAGE(0, c0*64)
    __syncthreads();

    for (int ci = 0; ci < nc_here; ++ci) {
        const int p = ci & 1;
        if (ci + 1 < nc_here) FSTAGE(p ^ 1, (c0 + ci + 1)*64)

        const int kvb = (c0 + ci) * 64;
        if (kvb <= qbw1 + 15)   // wave active while kv intersects causal range
            attn_step2(aq00, aq01, aq10, aq11, o0, o1, osum0, osum1, m0, m1,
                       Kl[p], Vl[p], kvb, qbw0, qbw1, lr, lg);

        __syncthreads();        // drains this iter's reads AND next tile's DMA
    }
#undef FSTAGE

    // combine per-lg osum partials (m is lg-uniform by construction)
    osum0 += __shfl_xor(osum0, 16);
    osum0 += __shfl_xor(osum0, 32);
    osum1 += __shfl_xor(osum1, 16);
    osum1 += __shfl_xor(osum1, 32);

    // write partials: bf16 O (unnormalized), fp32 m/sum per row
    const size_t slot = (size_t)bh * PARTS_PER_BH + x;
    u16*   po = part_o  + (slot << 13);          // [128][64]
    float* pm = part_ms + (slot << 8);           // [128][2]
    #pragma unroll
    for (int db = 0; db < 4; ++db)
        #pragma unroll
        for (int r = 0; r < 4; ++r) {
            po[(wid*32      + lg*4 + r)*64 + db*16 + lr] = f2bf(o0[db][r]);
            po[(wid*32 + 16 + lg*4 + r)*64 + db*16 + lr] = f2bf(o1[db][r]);
        }
    if (lane < 16) {
        pm[(wid*32      + lane)*2 + 0] = m0;
        pm[(wid*32      + lane)*2 + 1] = osum0;
        pm[(wid*32 + 16 + lane)*2 + 0] = m1;
        pm[(wid*32 + 16 + lane)*2 + 1] = osum1;
    }
}

// Merge <=4 chunk partials per (bh, t); write bf16 attn (B,S,D).
// NOTE: m values are in log2 domain -> exp2f.  All-masked partials carry
// m=0, osum=0: they contribute 0 to S and acc (weights stay consistent).
__global__ __launch_bounds__(256)
void merge_kernel(const u16* __restrict__ part_o, const float* __restrict__ part_ms,
                  u16* __restrict__ attb)
{
    const int t   = blockIdx.x;             // 0..15
    const int bh  = blockIdx.y;             // 0..31
    const int nch = min(4, (2*(t+1) + 7) >> 3);
    const int basex = t < 4 ? t : t < 8 ? 4 + 2*(t-4) : t < 12 ? 12 + 3*(t-8) : 24 + 4*(t-12);

    const int row = threadIdx.x >> 1;       // 0..127
    const int cb  = (threadIdx.x & 1) * 32; // col base

    float mm[4], ss[4];
    float M = -INFINITY;
    for (int c = 0; c < nch; ++c) {
        const size_t slot = (size_t)bh * PARTS_PER_BH + basex + c;
        mm[c] = part_ms[(slot << 8) + row*2 + 0];
        ss[c] = part_ms[(slot << 8) + row*2 + 1];
        M = fmaxf(M, mm[c]);
    }
    float S = 0.f;
    float acc[32];
    #pragma unroll
    for (int j = 0; j < 32; ++j) acc[j] = 0.f;
    for (int c = 0; c < nch; ++c) {
        const float w = exp2f(mm[c] - M);
        S += w * ss[c];
        const size_t slot = (size_t)bh * PARTS_PER_BH + basex + c;
        const u16* po = part_o + (slot << 13) + row*64 + cb;
        #pragma unroll
        for (int g = 0; g < 4; ++g) {
            short8 v = *(const short8*)(po + g*8);
            #pragma unroll
            for (int j = 0; j < 8; ++j)
                acc[g*8 + j] += w * bf2f((u16)v[j]);
        }
    }
    const float inv = 1.f / S;
    const int b = bh >> 4, h = bh & 15;
    const int grow = t*128 + row;
    u16* dst = attb + ((size_t)(b*SEQ + grow))*D_MODEL + h*64 + cb;
    #pragma unroll
    for (int g = 0; g < 4; ++g) {
        short8 ov;
        #pragma unroll
        for (int j = 0; j < 8; ++j) ov[j] = (short)f2bf(acc[g*8 + j] * inv);
        *(short8*)(dst + g*8) = ov;
    }
}

extern "C" void kernel_launch(void* const* d_in, const int* in_sizes, int n_in,
                              void* d_out, int out_size, void* d_ws, size_t ws_size,
                              hipStream_t stream)
{
    const float* q   = (const float*)d_in[0];
    const float* k   = (const float*)d_in[1];
    const float* v   = (const float*)d_in[2];
    // d_in[3] = mask (causal tril) — computed analytically in-kernel
    const float* w_q = (const float*)d_in[4];
    const float* b_q = (const float*)d_in[5];
    const float* w_k = (const float*)d_in[6];
    const float* b_k = (const float*)d_in[7];
    const float* w_v = (const float*)d_in[8];
    const float* b_v = (const float*)d_in[9];
    const float* w_o = (const float*)d_in[10];
    const float* b_o = (const float*)d_in[11];

    char* ws = (char*)d_ws;
    const size_t MB = 1024*1024;
    u16* Qh   = (u16*)(ws +  0*MB);   // bf16 (B,H,S,dk)
    u16* Kh   = (u16*)(ws +  8*MB);   // bf16 (B,H,S,dk)
    u16* Vt   = (u16*)(ws + 16*MB);   // bf16 (B,H,dk,S), vperm'd columns
    u16* qb   = (u16*)(ws + 24*MB);   // bf16 (M,K); aliased as attb after Q-proj
    u16* kb   = (u16*)(ws + 32*MB);
    u16* vb   = (u16*)(ws + 40*MB);
    u16* wqb  = (u16*)(ws + 48*MB);
    u16* wkb  = (u16*)(ws + 50*MB);
    u16* wvb  = (u16*)(ws + 52*MB);
    u16* wob  = (u16*)(ws + 54*MB);   // ws usage: 56 MiB
    u16* attb = qb;                   // qb dead after Q projection
    // flash partials overlay kb..wvb (dead after qkv GEMM):
    u16*   part_o  = (u16*)(ws + 32*MB);   // 1280 slots x 16KB = 20 MB (32..52)
    float* part_ms = (float*)(ws + 52*MB); // 1280 x 128 x 2 f32 = 1.25 MB (52..53.25)

    const int M = BATCH * SEQ, N = D_MODEL, K = D_MODEL;

    convert_kernel<<<2048, 256, 0, stream>>>(q, k, v, w_q, w_k, w_v, w_o,
                                             qb, kb, vb, wqb, wkb, wvb, wob);
    gemm_qkv_kernel<<<dim3(M/128, N/128, 3), 256, 0, stream>>>(
        qb, kb, vb, wqb, wkb, wvb, b_q, b_k, b_v, Qh, Kh, Vt, M, N, K);
    flash_split_kernel<<<dim3(PARTS_PER_BH, BATCH*N_HEADS), 256, 0, stream>>>(
        Qh, Kh, Vt, part_o, part_ms);
    merge_kernel<<<dim3(NT128, BATCH*N_HEADS), 256, 0, stream>>>(part_o, part_ms, attb);
    gemm_out_kernel<<<dim3(M/64, N/64), 256, 0, stream>>>(attb, wob, b_o, (float*)d_out, M, N, K);
}

// Round 20
// 127.618 us; speedup vs baseline: 1.0672x; 1.0672x over previous
//
#include <hip/hip_runtime.h>
#include <math.h>

#define D_MODEL 1024
#define N_HEADS 16
#define DKH     64
#define BATCH   2
#define SEQ     2048
#define NT128   (SEQ/128)         // 16 q-tiles of 128
#define PARTS_PER_BH 40           // sum over t of ceil(2(t+1)/8)

typedef unsigned short u16;
typedef unsigned long long u64;
typedef __attribute__((ext_vector_type(8))) short short8;
typedef __attribute__((ext_vector_type(4))) short s4v;
typedef __attribute__((ext_vector_type(4))) float f32x4;

__device__ __forceinline__ u16 f2bf(float f) {
    unsigned u = __float_as_uint(f);
    u += 0x7fffu + ((u >> 16) & 1u);
    return (u16)(u >> 16);
}
__device__ __forceinline__ float bf2f(u16 x) {
    return __int_as_float(((int)x) << 16);
}

// raw v_exp_f32 (2^x). args bounded; denorm-range flush is harmless here.
__device__ __forceinline__ float fexp2(float x) {
#if __has_builtin(__builtin_amdgcn_exp2f)
    return __builtin_amdgcn_exp2f(x);
#else
    return exp2f(x);
#endif
}

__device__ __forceinline__ void gll16(const void* g, void* l) {
    __builtin_amdgcn_global_load_lds((const __attribute__((address_space(1))) void*)g,
                                     (__attribute__((address_space(3))) void*)l, 16, 0, 0);
}

// 16x16x16 bf16 MFMA (K=16): builtin if present, else raw asm.
__device__ __forceinline__ f32x4 mfma16(s4v a, s4v b, f32x4 c) {
#if __has_builtin(__builtin_amdgcn_mfma_f32_16x16x16bf16_1k)
    return __builtin_amdgcn_mfma_f32_16x16x16bf16_1k(a, b, c, 0, 0, 0);
#elif __has_builtin(__builtin_amdgcn_mfma_f32_16x16x16_bf16)
    return __builtin_amdgcn_mfma_f32_16x16x16_bf16(a, b, c, 0, 0, 0);
#else
    f32x4 d;
    asm("v_mfma_f32_16x16x16_bf16 %0, %1, %2, %3" : "=v"(d) : "v"(a), "v"(b), "v"(c));
    return d;
#endif
}

// V column permutation baked into Vt: 4-elem granularity so PV ds_read_b64
// gets 4 bits of lane->bank variation (conflict-free; verified: 4.3M -> 0).
__device__ __forceinline__ int vperm(int d) {
    return ((d & 7) << 3) | (((d >> 3) & 1) << 2);
}

// ---------------------------------------------------------------------------
// fp32 -> bf16 convert: q,k,v (4M elems each) + w_q,w_k,w_v,w_o (1M each)
// ---------------------------------------------------------------------------
__global__ __launch_bounds__(256)
void convert_kernel(const float* __restrict__ q, const float* __restrict__ k,
                    const float* __restrict__ v, const float* __restrict__ wq,
                    const float* __restrict__ wk, const float* __restrict__ wv,
                    const float* __restrict__ wo,
                    u16* __restrict__ qb, u16* __restrict__ kb, u16* __restrict__ vb,
                    u16* __restrict__ wqb, u16* __restrict__ wkb,
                    u16* __restrict__ wvb, u16* __restrict__ wob)
{
    const size_t NV = ((size_t)16 << 20) >> 3;   // total 16M elems in vec8 units
    for (size_t i = (size_t)blockIdx.x * blockDim.x + threadIdx.x; i < NV;
         i += (size_t)gridDim.x * blockDim.x) {
        const size_t e = i << 3;
        const float* s; u16* d; size_t off;
        if (e < ((size_t)12 << 20)) {
            const int seg = (int)(e >> 22);
            off = e & (((size_t)1 << 22) - 1);
            s = seg == 0 ? q : seg == 1 ? k : v;
            d = seg == 0 ? qb : seg == 1 ? kb : vb;
        } else {
            const size_t r = e - ((size_t)12 << 20);
            const int seg = (int)(r >> 20);
            off = r & (((size_t)1 << 20) - 1);
            s = seg == 0 ? wq : seg == 1 ? wk : seg == 2 ? wv : wo;
            d = seg == 0 ? wqb : seg == 1 ? wkb : seg == 2 ? wvb : wob;
        }
        const float4 f0 = *(const float4*)(s + off);
        const float4 f1 = *(const float4*)(s + off + 4);
        short8 o;
        o[0]=(short)f2bf(f0.x); o[1]=(short)f2bf(f0.y); o[2]=(short)f2bf(f0.z); o[3]=(short)f2bf(f0.w);
        o[4]=(short)f2bf(f1.x); o[5]=(short)f2bf(f1.y); o[6]=(short)f2bf(f1.z); o[7]=(short)f2bf(f1.w);
        *(short8*)(d + off) = o;
    }
}

// ---------------------------------------------------------------------------
// GEMM core: 128x128 tile, BK=32, 4 waves, global_load_lds staging.
// ---------------------------------------------------------------------------
#define GEMM_PREAMBLE                                                            \
    __shared__ __align__(16) u16 As[2][128][32];                                 \
    __shared__ __align__(16) u16 Bs[2][128][32];                                 \
    const int tid  = threadIdx.x;                                                \
    const int lane = tid & 63;                                                   \
    const int wid  = tid >> 6;                                                   \
    const int wm   = wid >> 1, wn = wid & 1;                                     \
    const int lr   = lane & 15, lg = lane >> 4;                                  \
    const int mb   = blockIdx.x * 128, nb = blockIdx.y * 128;                    \
    const int g_row = lane >> 2;                                                 \
    const int g_col = (lane & 3) << 3;                                           \
    const u16* Ab = A  + (size_t)mb * K;                                         \
    const u16* Bb = Bw + (size_t)nb * K;                                         \
    f32x4 acc[4][4];                                                             \
    _Pragma("unroll")                                                            \
    for (int i = 0; i < 4; ++i)                                                  \
        _Pragma("unroll")                                                        \
        for (int j = 0; j < 4; ++j) { f32x4 z = {0.f,0.f,0.f,0.f}; acc[i][j] = z; }

#define STAGE(buf, kt)                                                           \
    {                                                                            \
        _Pragma("unroll")                                                        \
        for (int t = 0; t < 2; ++t) {                                            \
            const int r0 = t*64 + wid*16;                                        \
            gll16(&Ab[(size_t)(r0 + g_row)*K + (kt) + g_col], &As[buf][r0][0]);  \
            gll16(&Bb[(size_t)(r0 + g_row)*K + (kt) + g_col], &Bs[buf][r0][0]);  \
        }                                                                        \
    }

#define GEMM_MAINLOOP                                                            \
    STAGE(0, 0)                                                                  \
    __syncthreads();                                                             \
    const int NK = K >> 5;                                                       \
    for (int it = 0; it < NK; ++it) {                                            \
        const int c = it & 1;                                                    \
        if (it + 1 < NK) STAGE(c ^ 1, (it + 1) << 5)                             \
        short8 a[4], b[4];                                                       \
        _Pragma("unroll")                                                        \
        for (int i = 0; i < 4; ++i) a[i] = *(const short8*)&As[c][wm*64 + i*16 + lr][lg*8]; \
        _Pragma("unroll")                                                        \
        for (int j = 0; j < 4; ++j) b[j] = *(const short8*)&Bs[c][wn*64 + j*16 + lr][lg*8]; \
        _Pragma("unroll")                                                        \
        for (int i = 0; i < 4; ++i)                                              \
            _Pragma("unroll")                                                    \
            for (int j = 0; j < 4; ++j)                                          \
                acc[i][j] = __builtin_amdgcn_mfma_f32_16x16x32_bf16(a[i], b[j], acc[i][j], 0, 0, 0); \
        __syncthreads();                                                         \
    }

// Batched Q/K/V projection: blockIdx.z selects {q,k,v}.  3 blocks/CU.
// Q carries 0.125 * log2(e) so flash softmax runs in exp2 domain.
// V (z==2) is stored transposed (B,H,dk,S) with the vperm column shuffle
// baked in (bank-conflict-free PV b64 reads in flash).
__global__ __launch_bounds__(256, 3)
void gemm_qkv_kernel(const u16* __restrict__ qb, const u16* __restrict__ kb,
                     const u16* __restrict__ vb, const u16* __restrict__ wqb,
                     const u16* __restrict__ wkb, const u16* __restrict__ wvb,
                     const float* __restrict__ b_q, const float* __restrict__ b_k,
                     const float* __restrict__ b_v,
                     u16* __restrict__ Qh, u16* __restrict__ Kh, u16* __restrict__ Vt,
                     int M, int N, int K)
{
    const int z = blockIdx.z;
    const u16* A    = z == 0 ? qb  : z == 1 ? kb  : vb;
    const u16* Bw   = z == 0 ? wqb : z == 1 ? wkb : wvb;
    const float* bias = z == 0 ? b_q : z == 1 ? b_k : b_v;
    u16* dst        = z == 0 ? Qh  : z == 1 ? Kh  : Vt;
    const float scale = z == 0 ? 0.18033688f : 1.0f;  // 0.125 * log2(e)

    GEMM_PREAMBLE
    GEMM_MAINLOOP

    #pragma unroll
    for (int i = 0; i < 4; ++i) {
        #pragma unroll
        for (int j = 0; j < 4; ++j) {
            const int mbase = mb + wm*64 + i*16 + lg*4;
            const int n     = nb + wn*64 + j*16 + lr;
            const float bn  = bias[n];
            const int h = n >> 6, d = n & 63;
            #pragma unroll
            for (int r = 0; r < 4; ++r) {
                const int m = mbase + r;
                const int b = m >> 11, s = m & (SEQ - 1);
                const float val = (acc[i][j][r] + bn) * scale;
                if (z == 2) {   // V transposed (B,H,dk,S), vperm'd columns
                    const int sp = (s & ~63) | ((s & 63) ^ vperm(d));
                    dst[(((size_t)(b*N_HEADS + h))*DKH + d)*SEQ + sp] = f2bf(val);
                } else {        // Q,K (B,H,S,dk)
                    dst[(((size_t)(b*N_HEADS + h))*SEQ + s)*DKH + d] = f2bf(val);
                }
            }
        }
    }
}

// Output projection: 64x64 tile -> 1024 blocks (4/CU co-residency; measured
// ~2.7us better than 128x64 -- this kernel is latency-limited).
__global__ __launch_bounds__(256)
void gemm_out_kernel(const u16* __restrict__ A, const u16* __restrict__ Bw,
                     const float* __restrict__ bias, float* __restrict__ dst,
                     int M, int N, int K)
{
    __shared__ __align__(16) u16 As[2][64][32];
    __shared__ __align__(16) u16 Bs[2][64][32];

    const int tid  = threadIdx.x;
    const int lane = tid & 63;
    const int wid  = tid >> 6;                   // 0..3
    const int wm   = wid >> 1, wn = wid & 1;     // 2x2 waves over 64x64
    const int lr   = lane & 15, lg = lane >> 4;
    const int mb   = blockIdx.x * 64, nb = blockIdx.y * 64;
    const int g_row = lane >> 2;                 // 0..15
    const int g_col = (lane & 3) << 3;

    const u16* Ab = A  + (size_t)mb * K;
    const u16* Bb = Bw + (size_t)nb * K;

    f32x4 acc[2][2];
    #pragma unroll
    for (int i = 0; i < 2; ++i)
        #pragma unroll
        for (int j = 0; j < 2; ++j) { f32x4 z = {0.f,0.f,0.f,0.f}; acc[i][j] = z; }

#define OSTAGE(buf, kt)                                                          \
    {                                                                            \
        gll16(&Ab[(size_t)(wid*16 + g_row)*K + (kt) + g_col], &As[buf][wid*16][0]); \
        gll16(&Bb[(size_t)(wid*16 + g_row)*K + (kt) + g_col], &Bs[buf][wid*16][0]); \
    }

    OSTAGE(0, 0)
    __syncthreads();

    const int NK = K >> 5;
    for (int it = 0; it < NK; ++it) {
        const int c = it & 1;
        if (it + 1 < NK) OSTAGE(c ^ 1, (it + 1) << 5)

        short8 a[2], b[2];
        #pragma unroll
        for (int i = 0; i < 2; ++i) a[i] = *(const short8*)&As[c][wm*32 + i*16 + lr][lg*8];
        #pragma unroll
        for (int j = 0; j < 2; ++j) b[j] = *(const short8*)&Bs[c][wn*32 + j*16 + lr][lg*8];
        #pragma unroll
        for (int i = 0; i < 2; ++i)
            #pragma unroll
            for (int j = 0; j < 2; ++j)
                acc[i][j] = __builtin_amdgcn_mfma_f32_16x16x32_bf16(a[i], b[j], acc[i][j], 0, 0, 0);

        __syncthreads();
    }
#undef OSTAGE

    #pragma unroll
    for (int i = 0; i < 2; ++i) {
        #pragma unroll
        for (int j = 0; j < 2; ++j) {
            const int mbase = mb + wm*32 + i*16 + lg*4;
            const int n     = nb + wn*32 + j*16 + lr;
            const float bn  = bias[n];
            #pragma unroll
            for (int r = 0; r < 4; ++r)
                dst[(size_t)(mbase + r) * N + n] = acc[i][j][r] + bn;
        }
    }
}

// ---------------------------------------------------------------------------
// one attention step, SPECULATIVE-EXP form: 16 q rows x 64 kv, exp2 domain.
// -m_run is folded into the QK accumulator init, so st' = score - m comes out
// of the MFMA directly.  P = exp2(st') is computed immediately per c-block
// (no cross-c max join, no subs): 4 independent QK->exp->cvt->PV chains.
// The max only feeds a POST-HOC ballot; if any lane's tile max exceeded
// m+11.5, o/osum (which already include this tile at the old scale) are
// rescaled by exp2(-tm) and m advances.  m_run init 0 (not -inf).
// PV B-frags read from vperm'd Vl: conflict-free b64 (verified: 0 conflicts).
// ---------------------------------------------------------------------------
__device__ __forceinline__ void attn_step(
    const short8& aq0, const short8& aq1,
    f32x4 (&o)[4], float& osum, float& m_run,
    const u16 (*__restrict__ Kl)[64], const u16 (*__restrict__ Vl)[64],
    int kvb, int qbw, int lr, int lg)
{
    const int ksw  = (lr & 7) << 3;
    const int pvsw = vperm(lr);          // row d = db*16+lr -> d&15 == lr&15
    const float nm = -m_run;
    f32x4 st[4];
    __builtin_amdgcn_s_setprio(1);
    #pragma unroll
    for (int c = 0; c < 4; ++c) {
        const int kr = c*16 + lr;
        f32x4 z = {nm, nm, nm, nm};      // C-init = -m  ->  st' = score - m
        short8 k0 = *(const short8*)&Kl[kr][( 0 + lg*8) ^ ksw];
        short8 k1 = *(const short8*)&Kl[kr][(32 + lg*8) ^ ksw];
        z = __builtin_amdgcn_mfma_f32_16x16x32_bf16(k0, aq0, z, 0, 0, 0);  // A=K!
        z = __builtin_amdgcn_mfma_f32_16x16x32_bf16(k1, aq1, z, 0, 0, 0);
        st[c] = z;
    }
    __builtin_amdgcn_s_setprio(0);

    // causal mask: kv = kvb + c*16 + lg*4 + r, q = qbw + lr
    if (kvb + 63 > qbw) {
        #pragma unroll
        for (int c = 0; c < 4; ++c)
            #pragma unroll
            for (int r = 0; r < 4; ++r)
                if (kvb + c*16 + lg*4 + r > qbw + lr) st[c][r] = -INFINITY;
    }

    // speculative P = exp2(st') using OLD m; independent per c-block.
    // lane-local max tl only feeds the post-hoc ballot (off critical path).
    s4v av[4];
    float sum = 0.f;
    float tl = -INFINITY;
    #pragma unroll
    for (int c = 0; c < 4; ++c) {
        const float p0 = fexp2(st[c][0]);
        const float p1 = fexp2(st[c][1]);
        const float p2 = fexp2(st[c][2]);
        const float p3 = fexp2(st[c][3]);
        sum += (p0 + p1) + (p2 + p3);
        tl = fmaxf(tl, fmaxf(fmaxf(st[c][0], st[c][1]), fmaxf(st[c][2], st[c][3])));
        unsigned lo, hi;
        asm("v_cvt_pk_bf16_f32 %0, %1, %2" : "=v"(lo) : "v"(p0), "v"(p1));
        asm("v_cvt_pk_bf16_f32 %0, %1, %2" : "=v"(hi) : "v"(p2), "v"(p3));
        union { unsigned u[2]; s4v s; } uu;
        uu.u[0] = lo; uu.u[1] = hi;
        av[c] = uu.s;
    }
    osum += sum;

    // O += P @ V  (16 x mfma 16x16x16; B-frag = conflict-free b64 from Vl)
    __builtin_amdgcn_s_setprio(1);
    #pragma unroll
    for (int c = 0; c < 4; ++c) {
        #pragma unroll
        for (int db = 0; db < 4; ++db) {
            union { u64 q; s4v s; } bv;
            bv.q = *(const u64*)&Vl[db*16 + lr][(c*16 + lg*4) ^ pvsw];
            o[db] = mfma16(av[c], bv.s, o[db]);
        }
    }
    __builtin_amdgcn_s_setprio(0);

    // post-hoc rescale (rare): this tile's contributions are already in
    // o/osum at the old scale, so scaling EVERYTHING by exp2(-tm) re-bases
    // all history (including this tile) to m_new = m_old + tm.
    if (__any(tl > 11.5f)) {
        float tm = fmaxf(tl, __shfl_xor(tl, 16));
        tm = fmaxf(tm, __shfl_xor(tm, 32));
        tm = fmaxf(tm, 0.f);                 // never lower m
        const float f = fexp2(-tm);          // per q=lr
        m_run += tm;
        osum *= f;
        float af[4];
        #pragma unroll
        for (int r = 0; r < 4; ++r)
            af[r] = __shfl(f, (lg << 4) | (lg*4 + r));   // f of q=lg*4+r
        #pragma unroll
        for (int db = 0; db < 4; ++db)
            #pragma unroll
            for (int r = 0; r < 4; ++r) o[db][r] *= af[r];
    }
}

// ---------------------------------------------------------------------------
// Split-KV flash attention: block = (bh, q-tile t of 128 rows, kv-chunk of
// up to 8 64-wide tiles).  1280 uniform blocks, LPT order.  K/V staged by
// direct global_load_lds (K source column pre-swizzled; V layout pre-permuted
// at projection), double-buffered, ONE __syncthreads per kv-tile.  ~33KB LDS.
// 512 threads / 16 q-rows per wave: two shared-fragment attempts (R16, R19)
// both regressed via VGPR/occupancy loss -- wave count wins in this regime.
// No forced min-waves (R9: spill disaster).
// ---------------------------------------------------------------------------
__global__ __launch_bounds__(512)
void flash_split_kernel(const u16* __restrict__ Qh, const u16* __restrict__ Kh,
                        const u16* __restrict__ Vt, u16* __restrict__ part_o,
                        float* __restrict__ part_ms)
{
    __shared__ __align__(16) u16 Kl[2][64][64];
    __shared__ __align__(16) u16 Vl[2][64][64];

    const int x = 39 - blockIdx.x;          // LPT: largest chunks dispatch first
    int t, ch;
    if      (x <  4) { t = x;                 ch = 0;        }
    else if (x < 12) { t = 4 + ((x-4) >> 1);  ch = (x-4)&1;  }
    else if (x < 24) { t = 8 + (x-12)/3;      ch = (x-12)%3; }
    else             { t = 12 + ((x-24) >> 2); ch = (x-24)&3; }

    const int tid  = threadIdx.x;
    const int lane = tid & 63;
    const int wid  = tid >> 6;              // 0..7
    const int lr   = lane & 15, lg = lane >> 4;
    const int bh   = blockIdx.y;            // b*H + h
    const int qbw  = t*128 + wid*16;        // wave's first q row
    const size_t base = (size_t)bh * SEQ * DKH;

    const int c0      = ch * 8;             // first kv tile (64-wide) of chunk
    const int nc_here = min(8, 2*(t+1) - c0);

    // staging: wave wid DMAs rows wid*8..wid*8+7 of K and of V (1KB each).
    // K: global source column carries the XOR swizzle; LDS dest linear.
    // V: layout already permuted at projection -> linear source.
    const int srow8 = lane >> 3;                    // row within wave slab
    const int srow  = wid*8 + srow8;                // 0..63
    const int kcol  = ((lane & 7) << 3) ^ (srow8 << 3);   // K swizzled col
    const int vcol  = (lane & 7) << 3;                    // V linear col

#define FSTAGE(buf, kb)                                                          \
    {                                                                            \
        gll16(&Kh[base + (size_t)((kb) + srow)*DKH + kcol], &Kl[buf][wid*8][0]); \
        gll16(&Vt[base + (size_t)srow*SEQ + (kb) + vcol],  &Vl[buf][wid*8][0]);  \
    }

    short8 aq0 = *(const short8*)&Qh[base + (size_t)(qbw + lr)*DKH +  0 + lg*8];
    short8 aq1 = *(const short8*)&Qh[base + (size_t)(qbw + lr)*DKH + 32 + lg*8];

    f32x4 o[4];
    float osum = 0.f, m_run = 0.f;          // m init 0 (speculative-exp form)
    {
        f32x4 z = {0.f,0.f,0.f,0.f};
        #pragma unroll
        for (int db = 0; db < 4; ++db) o[db] = z;
    }

    FSTAGE(0, c0*64)
    __syncthreads();

    for (int ci = 0; ci < nc_here; ++ci) {
        const int p = ci & 1;
        if (ci + 1 < nc_here) FSTAGE(p ^ 1, (c0 + ci + 1)*64)

        const int kvb = (c0 + ci) * 64;
        if (kvb <= qbw + 15)    // wave active while kv range intersects causal
            attn_step(aq0, aq1, o, osum, m_run, Kl[p], Vl[p], kvb, qbw, lr, lg);

        __syncthreads();        // drains this iter's reads AND next tile's DMA
    }
#undef FSTAGE

    // combine per-lg osum partials (m_run is lg-uniform by construction)
    osum += __shfl_xor(osum, 16);
    osum += __shfl_xor(osum, 32);

    // write partials: bf16 O (unnormalized), fp32 m/sum per row
    const size_t slot = (size_t)bh * PARTS_PER_BH + x;
    u16*   po = part_o  + (slot << 13);          // [128][64]
    float* pm = part_ms + (slot << 8);           // [128][2]
    #pragma unroll
    for (int db = 0; db < 4; ++db)
        #pragma unroll
        for (int r = 0; r < 4; ++r)
            po[(wid*16 + lg*4 + r)*64 + db*16 + lr] = f2bf(o[db][r]);
    if (lane < 16) {
        pm[(wid*16 + lane)*2 + 0] = m_run;
        pm[(wid*16 + lane)*2 + 1] = osum;
    }
}

// Merge <=4 chunk partials per (bh, t); write bf16 attn (B,S,D).
// NOTE: m values are in log2 domain -> exp2f.  All-masked partials carry
// m=0, osum=0: they contribute 0 to S and acc (weights stay consistent).
__global__ __launch_bounds__(256)
void merge_kernel(const u16* __restrict__ part_o, const float* __restrict__ part_ms,
                  u16* __restrict__ attb)
{
    const int t   = blockIdx.x;             // 0..15
    const int bh  = blockIdx.y;             // 0..31
    const int nch = min(4, (2*(t+1) + 7) >> 3);
    const int basex = t < 4 ? t : t < 8 ? 4 + 2*(t-4) : t < 12 ? 12 + 3*(t-8) : 24 + 4*(t-12);

    const int row = threadIdx.x >> 1;       // 0..127
    const int cb  = (threadIdx.x & 1) * 32; // col base

    float mm[4], ss[4];
    float M = -INFINITY;
    for (int c = 0; c < nch; ++c) {
        const size_t slot = (size_t)bh * PARTS_PER_BH + basex + c;
        mm[c] = part_ms[(slot << 8) + row*2 + 0];
        ss[c] = part_ms[(slot << 8) + row*2 + 1];
        M = fmaxf(M, mm[c]);
    }
    float S = 0.f;
    float acc[32];
    #pragma unroll
    for (int j = 0; j < 32; ++j) acc[j] = 0.f;
    for (int c = 0; c < nch; ++c) {
        const float w = exp2f(mm[c] - M);
        S += w * ss[c];
        const size_t slot = (size_t)bh * PARTS_PER_BH + basex + c;
        const u16* po = part_o + (slot << 13) + row*64 + cb;
        #pragma unroll
        for (int g = 0; g < 4; ++g) {
            short8 v = *(const short8*)(po + g*8);
            #pragma unroll
            for (int j = 0; j < 8; ++j)
                acc[g*8 + j] += w * bf2f((u16)v[j]);
        }
    }
    const float inv = 1.f / S;
    const int b = bh >> 4, h = bh & 15;
    const int grow = t*128 + row;
    u16* dst = attb + ((size_t)(b*SEQ + grow))*D_MODEL + h*64 + cb;
    #pragma unroll
    for (int g = 0; g < 4; ++g) {
        short8 ov;
        #pragma unroll
        for (int j = 0; j < 8; ++j) ov[j] = (short)f2bf(acc[g*8 + j] * inv);
        *(short8*)(dst + g*8) = ov;
    }
}

extern "C" void kernel_launch(void* const* d_in, const int* in_sizes, int n_in,
                              void* d_out, int out_size, void* d_ws, size_t ws_size,
                              hipStream_t stream)
{
    const float* q   = (const float*)d_in[0];
    const float* k   = (const float*)d_in[1];
    const float* v   = (const float*)d_in[2];
    // d_in[3] = mask (causal tril) — computed analytically in-kernel
    const float* w_q = (const float*)d_in[4];
    const float* b_q = (const float*)d_in[5];
    const float* w_k = (const float*)d_in[6];
    const float* b_k = (const float*)d_in[7];
    const float* w_v = (const float*)d_in[8];
    const float* b_v = (const float*)d_in[9];
    const float* w_o = (const float*)d_in[10];
    const float* b_o = (const float*)d_in[11];

    char* ws = (char*)d_ws;
    const size_t MB = 1024*1024;
    u16* Qh   = (u16*)(ws +  0*MB);   // bf16 (B,H,S,dk)
    u16* Kh   = (u16*)(ws +  8*MB);   // bf16 (B,H,S,dk)
    u16* Vt   = (u16*)(ws + 16*MB);   // bf16 (B,H,dk,S), vperm'd columns
    u16* qb   = (u16*)(ws + 24*MB);   // bf16 (M,K); aliased as attb after Q-proj
    u16* kb   = (u16*)(ws + 32*MB);
    u16* vb   = (u16*)(ws + 40*MB);
    u16* wqb  = (u16*)(ws + 48*MB);
    u16* wkb  = (u16*)(ws + 50*MB);
    u16* wvb  = (u16*)(ws + 52*MB);
    u16* wob  = (u16*)(ws + 54*MB);   // ws usage: 56 MiB
    u16* attb = qb;                   // qb dead after Q projection
    // flash partials overlay kb..wvb (dead after qkv GEMM):
    u16*   part_o  = (u16*)(ws + 32*MB);   // 1280 slots x 16KB = 20 MB (32..52)
    float* part_ms = (float*)(ws + 52*MB); // 1280 x 128 x 2 f32 = 1.25 MB (52..53.25)

    const int M = BATCH * SEQ, N = D_MODEL, K = D_MODEL;

    convert_kernel<<<2048, 256, 0, stream>>>(q, k, v, w_q, w_k, w_v, w_o,
                                             qb, kb, vb, wqb, wkb, wvb, wob);
    gemm_qkv_kernel<<<dim3(M/128, N/128, 3), 256, 0, stream>>>(
        qb, kb, vb, wqb, wkb, wvb, b_q, b_k, b_v, Qh, Kh, Vt, M, N, K);
    flash_split_kernel<<<dim3(PARTS_PER_BH, BATCH*N_HEADS), 512, 0, stream>>>(
        Qh, Kh, Vt, part_o, part_ms);
    merge_kernel<<<dim3(NT128, BATCH*N_HEADS), 256, 0, stream>>>(part_o, part_ms, attb);
    gemm_out_kernel<<<dim3(M/64, N/64), 256, 0, stream>>>(attb, wob, b_o, (float*)d_out, M, N, K);
}

// Round 21
// 126.436 us; speedup vs baseline: 1.0772x; 1.0093x over previous
//
#include <hip/hip_runtime.h>
#include <math.h>

#define D_MODEL 1024
#define N_HEADS 16
#define DKH     64
#define BATCH   2
#define SEQ     2048
#define NT128   (SEQ/128)         // 16 q-tiles of 128
#define PARTS_PER_BH 40           // sum over t of ceil(2(t+1)/8)

typedef unsigned short u16;
typedef unsigned long long u64;
typedef __attribute__((ext_vector_type(8))) short short8;
typedef __attribute__((ext_vector_type(4))) short s4v;
typedef __attribute__((ext_vector_type(4))) float f32x4;

__device__ __forceinline__ u16 f2bf(float f) {
    unsigned u = __float_as_uint(f);
    u += 0x7fffu + ((u >> 16) & 1u);
    return (u16)(u >> 16);
}
__device__ __forceinline__ float bf2f(u16 x) {
    return __int_as_float(((int)x) << 16);
}

// raw v_exp_f32 (2^x). args bounded; denorm-range flush is harmless here.
__device__ __forceinline__ float fexp2(float x) {
#if __has_builtin(__builtin_amdgcn_exp2f)
    return __builtin_amdgcn_exp2f(x);
#else
    return exp2f(x);
#endif
}

__device__ __forceinline__ void gll16(const void* g, void* l) {
    __builtin_amdgcn_global_load_lds((const __attribute__((address_space(1))) void*)g,
                                     (__attribute__((address_space(3))) void*)l, 16, 0, 0);
}

// 16x16x16 bf16 MFMA (K=16): builtin if present, else raw asm.
__device__ __forceinline__ f32x4 mfma16(s4v a, s4v b, f32x4 c) {
#if __has_builtin(__builtin_amdgcn_mfma_f32_16x16x16bf16_1k)
    return __builtin_amdgcn_mfma_f32_16x16x16bf16_1k(a, b, c, 0, 0, 0);
#elif __has_builtin(__builtin_amdgcn_mfma_f32_16x16x16_bf16)
    return __builtin_amdgcn_mfma_f32_16x16x16_bf16(a, b, c, 0, 0, 0);
#else
    f32x4 d;
    asm("v_mfma_f32_16x16x16_bf16 %0, %1, %2, %3" : "=v"(d) : "v"(a), "v"(b), "v"(c));
    return d;
#endif
}

// V column permutation baked into Vt: 4-elem granularity so PV ds_read_b64
// gets 4 bits of lane->bank variation (conflict-free; verified: 4.3M -> 0).
__device__ __forceinline__ int vperm(int d) {
    return ((d & 7) << 3) | (((d >> 3) & 1) << 2);
}

// ---------------------------------------------------------------------------
// fp32 -> bf16 convert: q,k,v (4M elems each) + w_q,w_k,w_v,w_o (1M each)
// ---------------------------------------------------------------------------
__global__ __launch_bounds__(256)
void convert_kernel(const float* __restrict__ q, const float* __restrict__ k,
                    const float* __restrict__ v, const float* __restrict__ wq,
                    const float* __restrict__ wk, const float* __restrict__ wv,
                    const float* __restrict__ wo,
                    u16* __restrict__ qb, u16* __restrict__ kb, u16* __restrict__ vb,
                    u16* __restrict__ wqb, u16* __restrict__ wkb,
                    u16* __restrict__ wvb, u16* __restrict__ wob)
{
    const size_t NV = ((size_t)16 << 20) >> 3;   // total 16M elems in vec8 units
    for (size_t i = (size_t)blockIdx.x * blockDim.x + threadIdx.x; i < NV;
         i += (size_t)gridDim.x * blockDim.x) {
        const size_t e = i << 3;
        const float* s; u16* d; size_t off;
        if (e < ((size_t)12 << 20)) {
            const int seg = (int)(e >> 22);
            off = e & (((size_t)1 << 22) - 1);
            s = seg == 0 ? q : seg == 1 ? k : v;
            d = seg == 0 ? qb : seg == 1 ? kb : vb;
        } else {
            const size_t r = e - ((size_t)12 << 20);
            const int seg = (int)(r >> 20);
            off = r & (((size_t)1 << 20) - 1);
            s = seg == 0 ? wq : seg == 1 ? wk : seg == 2 ? wv : wo;
            d = seg == 0 ? wqb : seg == 1 ? wkb : seg == 2 ? wvb : wob;
        }
        const float4 f0 = *(const float4*)(s + off);
        const float4 f1 = *(const float4*)(s + off + 4);
        short8 o;
        o[0]=(short)f2bf(f0.x); o[1]=(short)f2bf(f0.y); o[2]=(short)f2bf(f0.z); o[3]=(short)f2bf(f0.w);
        o[4]=(short)f2bf(f1.x); o[5]=(short)f2bf(f1.y); o[6]=(short)f2bf(f1.z); o[7]=(short)f2bf(f1.w);
        *(short8*)(d + off) = o;
    }
}

// ---------------------------------------------------------------------------
// GEMM core: 128x128 tile, BK=32, 4 waves, global_load_lds staging.
// ---------------------------------------------------------------------------
#define GEMM_PREAMBLE                                                            \
    __shared__ __align__(16) u16 As[2][128][32];                                 \
    __shared__ __align__(16) u16 Bs[2][128][32];                                 \
    const int tid  = threadIdx.x;                                                \
    const int lane = tid & 63;                                                   \
    const int wid  = tid >> 6;                                                   \
    const int wm   = wid >> 1, wn = wid & 1;                                     \
    const int lr   = lane & 15, lg = lane >> 4;                                  \
    const int mb   = blockIdx.x * 128, nb = blockIdx.y * 128;                    \
    const int g_row = lane >> 2;                                                 \
    const int g_col = (lane & 3) << 3;                                           \
    const u16* Ab = A  + (size_t)mb * K;                                         \
    const u16* Bb = Bw + (size_t)nb * K;                                         \
    f32x4 acc[4][4];                                                             \
    _Pragma("unroll")                                                            \
    for (int i = 0; i < 4; ++i)                                                  \
        _Pragma("unroll")                                                        \
        for (int j = 0; j < 4; ++j) { f32x4 z = {0.f,0.f,0.f,0.f}; acc[i][j] = z; }

#define STAGE(buf, kt)                                                           \
    {                                                                            \
        _Pragma("unroll")                                                        \
        for (int t = 0; t < 2; ++t) {                                            \
            const int r0 = t*64 + wid*16;                                        \
            gll16(&Ab[(size_t)(r0 + g_row)*K + (kt) + g_col], &As[buf][r0][0]);  \
            gll16(&Bb[(size_t)(r0 + g_row)*K + (kt) + g_col], &Bs[buf][r0][0]);  \
        }                                                                        \
    }

#define GEMM_MAINLOOP                                                            \
    STAGE(0, 0)                                                                  \
    __syncthreads();                                                             \
    const int NK = K >> 5;                                                       \
    for (int it = 0; it < NK; ++it) {                                            \
        const int c = it & 1;                                                    \
        if (it + 1 < NK) STAGE(c ^ 1, (it + 1) << 5)                             \
        short8 a[4], b[4];                                                       \
        _Pragma("unroll")                                                        \
        for (int i = 0; i < 4; ++i) a[i] = *(const short8*)&As[c][wm*64 + i*16 + lr][lg*8]; \
        _Pragma("unroll")                                                        \
        for (int j = 0; j < 4; ++j) b[j] = *(const short8*)&Bs[c][wn*64 + j*16 + lr][lg*8]; \
        _Pragma("unroll")                                                        \
        for (int i = 0; i < 4; ++i)                                              \
            _Pragma("unroll")                                                    \
            for (int j = 0; j < 4; ++j)                                          \
                acc[i][j] = __builtin_amdgcn_mfma_f32_16x16x32_bf16(a[i], b[j], acc[i][j], 0, 0, 0); \
        __syncthreads();                                                         \
    }

// Batched Q/K/V projection: blockIdx.z selects {q,k,v}.  3 blocks/CU.
// Q carries 0.125 * log2(e) so flash softmax runs in exp2 domain.
// V (z==2) is stored transposed (B,H,dk,S) with the vperm column shuffle
// baked in (bank-conflict-free PV b64 reads in flash).
__global__ __launch_bounds__(256, 3)
void gemm_qkv_kernel(const u16* __restrict__ qb, const u16* __restrict__ kb,
                     const u16* __restrict__ vb, const u16* __restrict__ wqb,
                     const u16* __restrict__ wkb, const u16* __restrict__ wvb,
                     const float* __restrict__ b_q, const float* __restrict__ b_k,
                     const float* __restrict__ b_v,
                     u16* __restrict__ Qh, u16* __restrict__ Kh, u16* __restrict__ Vt,
                     int M, int N, int K)
{
    const int z = blockIdx.z;
    const u16* A    = z == 0 ? qb  : z == 1 ? kb  : vb;
    const u16* Bw   = z == 0 ? wqb : z == 1 ? wkb : wvb;
    const float* bias = z == 0 ? b_q : z == 1 ? b_k : b_v;
    u16* dst        = z == 0 ? Qh  : z == 1 ? Kh  : Vt;
    const float scale = z == 0 ? 0.18033688f : 1.0f;  // 0.125 * log2(e)

    GEMM_PREAMBLE
    GEMM_MAINLOOP

    #pragma unroll
    for (int i = 0; i < 4; ++i) {
        #pragma unroll
        for (int j = 0; j < 4; ++j) {
            const int mbase = mb + wm*64 + i*16 + lg*4;
            const int n     = nb + wn*64 + j*16 + lr;
            const float bn  = bias[n];
            const int h = n >> 6, d = n & 63;
            #pragma unroll
            for (int r = 0; r < 4; ++r) {
                const int m = mbase + r;
                const int b = m >> 11, s = m & (SEQ - 1);
                const float val = (acc[i][j][r] + bn) * scale;
                if (z == 2) {   // V transposed (B,H,dk,S), vperm'd columns
                    const int sp = (s & ~63) | ((s & 63) ^ vperm(d));
                    dst[(((size_t)(b*N_HEADS + h))*DKH + d)*SEQ + sp] = f2bf(val);
                } else {        // Q,K (B,H,S,dk)
                    dst[(((size_t)(b*N_HEADS + h))*SEQ + s)*DKH + d] = f2bf(val);
                }
            }
        }
    }
}

// Output projection: 64x64 tile -> 1024 blocks (4/CU co-residency; measured
// ~2.7us better than 128x64 -- this kernel is latency-limited).
__global__ __launch_bounds__(256)
void gemm_out_kernel(const u16* __restrict__ A, const u16* __restrict__ Bw,
                     const float* __restrict__ bias, float* __restrict__ dst,
                     int M, int N, int K)
{
    __shared__ __align__(16) u16 As[2][64][32];
    __shared__ __align__(16) u16 Bs[2][64][32];

    const int tid  = threadIdx.x;
    const int lane = tid & 63;
    const int wid  = tid >> 6;                   // 0..3
    const int wm   = wid >> 1, wn = wid & 1;     // 2x2 waves over 64x64
    const int lr   = lane & 15, lg = lane >> 4;
    const int mb   = blockIdx.x * 64, nb = blockIdx.y * 64;
    const int g_row = lane >> 2;                 // 0..15
    const int g_col = (lane & 3) << 3;

    const u16* Ab = A  + (size_t)mb * K;
    const u16* Bb = Bw + (size_t)nb * K;

    f32x4 acc[2][2];
    #pragma unroll
    for (int i = 0; i < 2; ++i)
        #pragma unroll
        for (int j = 0; j < 2; ++j) { f32x4 z = {0.f,0.f,0.f,0.f}; acc[i][j] = z; }

#define OSTAGE(buf, kt)                                                          \
    {                                                                            \
        gll16(&Ab[(size_t)(wid*16 + g_row)*K + (kt) + g_col], &As[buf][wid*16][0]); \
        gll16(&Bb[(size_t)(wid*16 + g_row)*K + (kt) + g_col], &Bs[buf][wid*16][0]); \
    }

    OSTAGE(0, 0)
    __syncthreads();

    const int NK = K >> 5;
    for (int it = 0; it < NK; ++it) {
        const int c = it & 1;
        if (it + 1 < NK) OSTAGE(c ^ 1, (it + 1) << 5)

        short8 a[2], b[2];
        #pragma unroll
        for (int i = 0; i < 2; ++i) a[i] = *(const short8*)&As[c][wm*32 + i*16 + lr][lg*8];
        #pragma unroll
        for (int j = 0; j < 2; ++j) b[j] = *(const short8*)&Bs[c][wn*32 + j*16 + lr][lg*8];
        #pragma unroll
        for (int i = 0; i < 2; ++i)
            #pragma unroll
            for (int j = 0; j < 2; ++j)
                acc[i][j] = __builtin_amdgcn_mfma_f32_16x16x32_bf16(a[i], b[j], acc[i][j], 0, 0, 0);

        __syncthreads();
    }
#undef OSTAGE

    #pragma unroll
    for (int i = 0; i < 2; ++i) {
        #pragma unroll
        for (int j = 0; j < 2; ++j) {
            const int mbase = mb + wm*32 + i*16 + lg*4;
            const int n     = nb + wn*32 + j*16 + lr;
            const float bn  = bias[n];
            #pragma unroll
            for (int r = 0; r < 4; ++r)
                dst[(size_t)(mbase + r) * N + n] = acc[i][j][r] + bn;
        }
    }
}

// ---------------------------------------------------------------------------
// one attention step, SPECULATIVE-EXP form: 16 q rows x 64 kv, exp2 domain.
// -m_run is folded into the QK accumulator init, so st' = score - m comes out
// of the MFMA directly.  P = exp2(st') is computed immediately per c-block
// (no cross-c max join, no subs): 4 independent QK->exp->cvt->PV chains.
// The max only feeds a POST-HOC ballot; if any lane's tile max exceeded
// m+11.5, o/osum (which already include this tile at the old scale) are
// rescaled by exp2(-tm) and m advances.  m_run init 0 (not -inf).
// PV B-frags read from vperm'd Vl: conflict-free b64 (verified: 0 conflicts).
// ---------------------------------------------------------------------------
__device__ __forceinline__ void attn_step(
    const short8& aq0, const short8& aq1,
    f32x4 (&o)[4], float& osum, float& m_run,
    const u16 (*__restrict__ Kl)[64], const u16 (*__restrict__ Vl)[64],
    int kvb, int qbw, int lr, int lg)
{
    const int ksw  = (lr & 7) << 3;
    const int pvsw = vperm(lr);          // row d = db*16+lr -> d&15 == lr&15
    const float nm = -m_run;
    f32x4 st[4];
    __builtin_amdgcn_s_setprio(1);
    #pragma unroll
    for (int c = 0; c < 4; ++c) {
        const int kr = c*16 + lr;
        f32x4 z = {nm, nm, nm, nm};      // C-init = -m  ->  st' = score - m
        short8 k0 = *(const short8*)&Kl[kr][( 0 + lg*8) ^ ksw];
        short8 k1 = *(const short8*)&Kl[kr][(32 + lg*8) ^ ksw];
        z = __builtin_amdgcn_mfma_f32_16x16x32_bf16(k0, aq0, z, 0, 0, 0);  // A=K!
        z = __builtin_amdgcn_mfma_f32_16x16x32_bf16(k1, aq1, z, 0, 0, 0);
        st[c] = z;
    }
    __builtin_amdgcn_s_setprio(0);

    // causal mask: kv = kvb + c*16 + lg*4 + r, q = qbw + lr
    if (kvb + 63 > qbw) {
        #pragma unroll
        for (int c = 0; c < 4; ++c)
            #pragma unroll
            for (int r = 0; r < 4; ++r)
                if (kvb + c*16 + lg*4 + r > qbw + lr) st[c][r] = -INFINITY;
    }

    // speculative P = exp2(st') using OLD m; independent per c-block.
    // lane-local max tl only feeds the post-hoc ballot (off critical path).
    s4v av[4];
    float sum = 0.f;
    float tl = -INFINITY;
    #pragma unroll
    for (int c = 0; c < 4; ++c) {
        const float p0 = fexp2(st[c][0]);
        const float p1 = fexp2(st[c][1]);
        const float p2 = fexp2(st[c][2]);
        const float p3 = fexp2(st[c][3]);
        sum += (p0 + p1) + (p2 + p3);
        tl = fmaxf(tl, fmaxf(fmaxf(st[c][0], st[c][1]), fmaxf(st[c][2], st[c][3])));
        unsigned lo, hi;
        asm("v_cvt_pk_bf16_f32 %0, %1, %2" : "=v"(lo) : "v"(p0), "v"(p1));
        asm("v_cvt_pk_bf16_f32 %0, %1, %2" : "=v"(hi) : "v"(p2), "v"(p3));
        union { unsigned u[2]; s4v s; } uu;
        uu.u[0] = lo; uu.u[1] = hi;
        av[c] = uu.s;
    }
    osum += sum;

    // O += P @ V  (16 x mfma 16x16x16; B-frag = conflict-free b64 from Vl)
    __builtin_amdgcn_s_setprio(1);
    #pragma unroll
    for (int c = 0; c < 4; ++c) {
        #pragma unroll
        for (int db = 0; db < 4; ++db) {
            union { u64 q; s4v s; } bv;
            bv.q = *(const u64*)&Vl[db*16 + lr][(c*16 + lg*4) ^ pvsw];
            o[db] = mfma16(av[c], bv.s, o[db]);
        }
    }
    __builtin_amdgcn_s_setprio(0);

    // post-hoc rescale (rare): this tile's contributions are already in
    // o/osum at the old scale, so scaling EVERYTHING by exp2(-tm) re-bases
    // all history (including this tile) to m_new = m_old + tm.
    if (__any(tl > 11.5f)) {
        float tm = fmaxf(tl, __shfl_xor(tl, 16));
        tm = fmaxf(tm, __shfl_xor(tm, 32));
        tm = fmaxf(tm, 0.f);                 // never lower m
        const float f = fexp2(-tm);          // per q=lr
        m_run += tm;
        osum *= f;
        float af[4];
        #pragma unroll
        for (int r = 0; r < 4; ++r)
            af[r] = __shfl(f, (lg << 4) | (lg*4 + r));   // f of q=lg*4+r
        #pragma unroll
        for (int db = 0; db < 4; ++db)
            #pragma unroll
            for (int r = 0; r < 4; ++r) o[db][r] *= af[r];
    }
}

// ---------------------------------------------------------------------------
// Split-KV flash attention: block = (bh, q-tile t of 128 rows, kv-chunk of
// up to 8 64-wide tiles).  1280 uniform blocks, LPT order.  K/V staged by
// direct global_load_lds (K source column pre-swizzled; V layout pre-permuted
// at projection), double-buffered, ONE __syncthreads per kv-tile.  ~33KB LDS.
// Single-chunk tiles (x<4, i.e. t<4) are normalized and written to attb
// directly in the epilogue (their merge pass would be a pure copy); these are
// the shortest blocks, sitting in the LPT drain tail, so the extra epilogue
// work is effectively free.  512 threads / 16 q-rows per wave (shared-frag
// attempts R16/R19 both regressed via VGPR/occupancy loss).  No forced
// min-waves (R9: spill disaster).
// ---------------------------------------------------------------------------
__global__ __launch_bounds__(512)
void flash_split_kernel(const u16* __restrict__ Qh, const u16* __restrict__ Kh,
                        const u16* __restrict__ Vt, u16* __restrict__ part_o,
                        float* __restrict__ part_ms, u16* __restrict__ attb)
{
    __shared__ __align__(16) u16 Kl[2][64][64];
    __shared__ __align__(16) u16 Vl[2][64][64];

    const int x = 39 - blockIdx.x;          // LPT: largest chunks dispatch first
    int t, ch;
    if      (x <  4) { t = x;                 ch = 0;        }
    else if (x < 12) { t = 4 + ((x-4) >> 1);  ch = (x-4)&1;  }
    else if (x < 24) { t = 8 + (x-12)/3;      ch = (x-12)%3; }
    else             { t = 12 + ((x-24) >> 2); ch = (x-24)&3; }

    const int tid  = threadIdx.x;
    const int lane = tid & 63;
    const int wid  = tid >> 6;              // 0..7
    const int lr   = lane & 15, lg = lane >> 4;
    const int bh   = blockIdx.y;            // b*H + h
    const int qbw  = t*128 + wid*16;        // wave's first q row
    const size_t base = (size_t)bh * SEQ * DKH;

    const int c0      = ch * 8;             // first kv tile (64-wide) of chunk
    const int nc_here = min(8, 2*(t+1) - c0);

    // staging: wave wid DMAs rows wid*8..wid*8+7 of K and of V (1KB each).
    // K: global source column carries the XOR swizzle; LDS dest linear.
    // V: layout already permuted at projection -> linear source.
    const int srow8 = lane >> 3;                    // row within wave slab
    const int srow  = wid*8 + srow8;                // 0..63
    const int kcol  = ((lane & 7) << 3) ^ (srow8 << 3);   // K swizzled col
    const int vcol  = (lane & 7) << 3;                    // V linear col

#define FSTAGE(buf, kb)                                                          \
    {                                                                            \
        gll16(&Kh[base + (size_t)((kb) + srow)*DKH + kcol], &Kl[buf][wid*8][0]); \
        gll16(&Vt[base + (size_t)srow*SEQ + (kb) + vcol],  &Vl[buf][wid*8][0]);  \
    }

    short8 aq0 = *(const short8*)&Qh[base + (size_t)(qbw + lr)*DKH +  0 + lg*8];
    short8 aq1 = *(const short8*)&Qh[base + (size_t)(qbw + lr)*DKH + 32 + lg*8];

    f32x4 o[4];
    float osum = 0.f, m_run = 0.f;          // m init 0 (speculative-exp form)
    {
        f32x4 z = {0.f,0.f,0.f,0.f};
        #pragma unroll
        for (int db = 0; db < 4; ++db) o[db] = z;
    }

    FSTAGE(0, c0*64)
    __syncthreads();

    for (int ci = 0; ci < nc_here; ++ci) {
        const int p = ci & 1;
        if (ci + 1 < nc_here) FSTAGE(p ^ 1, (c0 + ci + 1)*64)

        const int kvb = (c0 + ci) * 64;
        if (kvb <= qbw + 15)    // wave active while kv range intersects causal
            attn_step(aq0, aq1, o, osum, m_run, Kl[p], Vl[p], kvb, qbw, lr, lg);

        __syncthreads();        // drains this iter's reads AND next tile's DMA
    }
#undef FSTAGE

    // combine per-lg osum partials (m_run is lg-uniform by construction)
    osum += __shfl_xor(osum, 16);
    osum += __shfl_xor(osum, 32);

    if (x < 4) {
        // single-chunk tile (t = x, nch = 1): normalize + write attb directly
        const int b = bh >> 4, h = bh & 15;
        const float inv = 1.f / osum;        // per q = lane&15
        float invr[4];
        #pragma unroll
        for (int r = 0; r < 4; ++r)
            invr[r] = __shfl(inv, (lg << 4) | (lg*4 + r));   // inv of q=lg*4+r
        #pragma unroll
        for (int db = 0; db < 4; ++db)
            #pragma unroll
            for (int r = 0; r < 4; ++r) {
                const int s_ = qbw + lg*4 + r;
                attb[((size_t)(b*SEQ + s_))*D_MODEL + h*64 + db*16 + lr] =
                    f2bf(o[db][r] * invr[r]);
            }
    } else {
        // write partials: bf16 O (unnormalized), fp32 m/sum per row
        const size_t slot = (size_t)bh * PARTS_PER_BH + x;
        u16*   po = part_o  + (slot << 13);          // [128][64]
        float* pm = part_ms + (slot << 8);           // [128][2]
        #pragma unroll
        for (int db = 0; db < 4; ++db)
            #pragma unroll
            for (int r = 0; r < 4; ++r)
                po[(wid*16 + lg*4 + r)*64 + db*16 + lr] = f2bf(o[db][r]);
        if (lane < 16) {
            pm[(wid*16 + lane)*2 + 0] = m_run;
            pm[(wid*16 + lane)*2 + 1] = osum;
        }
    }
}

// Merge 2..4 chunk partials per (bh, t) for t = 4..15 (t<4 handled in flash);
// write bf16 attn (B,S,D).  m values are in log2 domain -> exp2f.  All-masked
// partials carry m=0, osum=0: they contribute 0 (weights stay consistent).
__global__ __launch_bounds__(256)
void merge_kernel(const u16* __restrict__ part_o, const float* __restrict__ part_ms,
                  u16* __restrict__ attb)
{
    const int t   = 4 + (int)blockIdx.x;    // 4..15
    const int bh  = blockIdx.y;             // 0..31
    const int nch = min(4, (2*(t+1) + 7) >> 3);
    const int basex = t < 8 ? 4 + 2*(t-4) : t < 12 ? 12 + 3*(t-8) : 24 + 4*(t-12);

    const int row = threadIdx.x >> 1;       // 0..127
    const int cb  = (threadIdx.x & 1) * 32; // col base

    float mm[4], ss[4];
    float M = -INFINITY;
    for (int c = 0; c < nch; ++c) {
        const size_t slot = (size_t)bh * PARTS_PER_BH + basex + c;
        mm[c] = part_ms[(slot << 8) + row*2 + 0];
        ss[c] = part_ms[(slot << 8) + row*2 + 1];
        M = fmaxf(M, mm[c]);
    }
    float S = 0.f;
    float acc[32];
    #pragma unroll
    for (int j = 0; j < 32; ++j) acc[j] = 0.f;
    for (int c = 0; c < nch; ++c) {
        const float w = exp2f(mm[c] - M);
        S += w * ss[c];
        const size_t slot = (size_t)bh * PARTS_PER_BH + basex + c;
        const u16* po = part_o + (slot << 13) + row*64 + cb;
        #pragma unroll
        for (int g = 0; g < 4; ++g) {
            short8 v = *(const short8*)(po + g*8);
            #pragma unroll
            for (int j = 0; j < 8; ++j)
                acc[g*8 + j] += w * bf2f((u16)v[j]);
        }
    }
    const float inv = 1.f / S;
    const int b = bh >> 4, h = bh & 15;
    const int grow = t*128 + row;
    u16* dst = attb + ((size_t)(b*SEQ + grow))*D_MODEL + h*64 + cb;
    #pragma unroll
    for (int g = 0; g < 4; ++g) {
        short8 ov;
        #pragma unroll
        for (int j = 0; j < 8; ++j) ov[j] = (short)f2bf(acc[g*8 + j] * inv);
        *(short8*)(dst + g*8) = ov;
    }
}

extern "C" void kernel_launch(void* const* d_in, const int* in_sizes, int n_in,
                              void* d_out, int out_size, void* d_ws, size_t ws_size,
                              hipStream_t stream)
{
    const float* q   = (const float*)d_in[0];
    const float* k   = (const float*)d_in[1];
    const float* v   = (const float*)d_in[2];
    // d_in[3] = mask (causal tril) — computed analytically in-kernel
    const float* w_q = (const float*)d_in[4];
    const float* b_q = (const float*)d_in[5];
    const float* w_k = (const float*)d_in[6];
    const float* b_k = (const float*)d_in[7];
    const float* w_v = (const float*)d_in[8];
    const float* b_v = (const float*)d_in[9];
    const float* w_o = (const float*)d_in[10];
    const float* b_o = (const float*)d_in[11];

    char* ws = (char*)d_ws;
    const size_t MB = 1024*1024;
    u16* Qh   = (u16*)(ws +  0*MB);   // bf16 (B,H,S,dk)
    u16* Kh   = (u16*)(ws +  8*MB);   // bf16 (B,H,S,dk)
    u16* Vt   = (u16*)(ws + 16*MB);   // bf16 (B,H,dk,S), vperm'd columns
    u16* qb   = (u16*)(ws + 24*MB);   // bf16 (M,K); aliased as attb after Q-proj
    u16* kb   = (u16*)(ws + 32*MB);
    u16* vb   = (u16*)(ws + 40*MB);
    u16* wqb  = (u16*)(ws + 48*MB);
    u16* wkb  = (u16*)(ws + 50*MB);
    u16* wvb  = (u16*)(ws + 52*MB);
    u16* wob  = (u16*)(ws + 54*MB);   // ws usage: 56 MiB
    u16* attb = qb;                   // qb dead after Q projection
    // flash partials overlay kb..wvb (dead after qkv GEMM):
    u16*   part_o  = (u16*)(ws + 32*MB);   // 1280 slots x 16KB = 20 MB (32..52)
    float* part_ms = (float*)(ws + 52*MB); // 1280 x 128 x 2 f32 = 1.25 MB (52..53.25)

    const int M = BATCH * SEQ, N = D_MODEL, K = D_MODEL;

    convert_kernel<<<2048, 256, 0, stream>>>(q, k, v, w_q, w_k, w_v, w_o,
                                             qb, kb, vb, wqb, wkb, wvb, wob);
    gemm_qkv_kernel<<<dim3(M/128, N/128, 3), 256, 0, stream>>>(
        qb, kb, vb, wqb, wkb, wvb, b_q, b_k, b_v, Qh, Kh, Vt, M, N, K);
    flash_split_kernel<<<dim3(PARTS_PER_BH, BATCH*N_HEADS), 512, 0, stream>>>(
        Qh, Kh, Vt, part_o, part_ms, attb);
    merge_kernel<<<dim3(NT128 - 4, BATCH*N_HEADS), 256, 0, stream>>>(part_o, part_ms, attb);
    gemm_out_kernel<<<dim3(M/64, N/64), 256, 0, stream>>>(attb, wob, b_o, (float*)d_out, M, N, K);
}